// Round 1
// baseline (2983.943 us; speedup 1.0000x reference)
//
#include <hip/hip_runtime.h>
#include <float.h>
#include <math.h>

// Problem constants
#define D_REAL 2331   // 259 channels * 3 * 3 patch
#define D_PAD  2336   // multiple of BD=16
#define N_REAL 7225   // 85*85 patches
#define N_PAD  7296   // 57*128, multiple of tile width
#define JTILES 57
#define ITILES 57
#define BD     16

// ---------------------------------------------------------------------------
// zero norm2 accumulator array + loss accumulator
__global__ void zero_ws(float* __restrict__ norm2, double* __restrict__ accum) {
    int i = blockIdx.x * blockDim.x + threadIdx.x;
    if (i < N_PAD) norm2[i] = 0.f;
    if (i == 0) *accum = 0.0;
}

// ---------------------------------------------------------------------------
// Build patch matrix P (D_PAD x N_PAD, row-major) from resp (256,256,256) and
// map (3,1024,1024). Channel c<256 -> resp; c in 256..258 -> 50 * avgpool4(map).
// P[d][n], d = c*9 + p*3 + q, n = u*85 + v, element = sr[c][3u+p][3v+q].
__global__ void build_patches(const float* __restrict__ resp,
                              const float* __restrict__ map,
                              float* __restrict__ P) {
    int idx = blockIdx.x * blockDim.x + threadIdx.x;
    if (idx >= D_PAD * N_PAD) return;
    int d = idx / N_PAD;
    int n = idx - d * N_PAD;
    float val = 0.f;
    if (d < D_REAL && n < N_REAL) {
        int c = d / 9;
        int r = d - c * 9;
        int p = r / 3, q = r - p * 3;
        int u = n / 85, v = n - u * 85;
        int row = 3 * u + p, col = 3 * v + q;   // in [0,255)
        if (c < 256) {
            val = resp[((size_t)c * 256 + row) * 256 + col];
        } else {
            const float* mp = map + (size_t)(c - 256) * 1024 * 1024
                                  + (size_t)(row * 4) * 1024 + (size_t)(col * 4);
            float s = 0.f;
            #pragma unroll
            for (int a = 0; a < 4; a++) {
                #pragma unroll
                for (int b = 0; b < 4; b++) s += mp[a * 1024 + b];
            }
            val = 50.0f * 0.0625f * s;   // MAP_CHANNEL_WEIGHT * mean * channel_count(=1)
        }
    }
    P[idx] = val;
}

// ---------------------------------------------------------------------------
// Column squared-norm partial sums (atomicAdd into norm2). 9 chunks of 259 rows.
__global__ void norm_partial(const float* __restrict__ P, float* __restrict__ norm2) {
    int n = blockIdx.x * blockDim.x + threadIdx.x;
    if (n >= N_PAD) return;
    int d0 = blockIdx.y * 259;
    float s = 0.f;
    for (int d = d0; d < d0 + 259; d++) {
        float v = P[(size_t)d * N_PAD + n];
        s = fmaf(v, v, s);
    }
    atomicAdd(&norm2[n], s);
}

__global__ void norm_fin(float* __restrict__ norm2) {
    int n = blockIdx.x * blockDim.x + threadIdx.x;
    if (n >= N_PAD) return;
    norm2[n] = (n < N_REAL) ? rsqrtf(norm2[n]) : 0.f;
}

// ---------------------------------------------------------------------------
// Fused GEMM + per-row argmax over this block's 128-j tile.
// sim[i][j] = dot(S[:,i], I[:,j]) * sinv[j]   (row scale img_norm_inv[i] > 0
// dropped: cannot change argmax along j).
// Output: per (j-tile, i): best value + best global j index.
__global__ __launch_bounds__(256) void gemm_argmax(
        const float* __restrict__ S, const float* __restrict__ I,
        const float* __restrict__ sinv,
        float* __restrict__ pval, int* __restrict__ pidx) {
    __shared__ float Ssh[BD][128];
    __shared__ float Ish[BD][128];
    const int i0 = blockIdx.x * 128;
    const int j0 = blockIdx.y * 128;
    const int tid = threadIdx.x;
    const int tx = tid & 15, ty = tid >> 4;

    float acc[8][8];
    #pragma unroll
    for (int a = 0; a < 8; a++)
        #pragma unroll
        for (int b = 0; b < 8; b++) acc[a][b] = 0.f;

    const int r  = tid >> 5;          // 0..7
    const int cc = (tid & 31) << 2;   // 0..124 step 4

    for (int d0 = 0; d0 < D_PAD; d0 += BD) {
        const float* Sp = S + (size_t)d0 * N_PAD + i0;
        const float* Ip = I + (size_t)d0 * N_PAD + j0;
        *(float4*)&Ssh[r][cc]     = *(const float4*)&Sp[(size_t)r * N_PAD + cc];
        *(float4*)&Ssh[r + 8][cc] = *(const float4*)&Sp[(size_t)(r + 8) * N_PAD + cc];
        *(float4*)&Ish[r][cc]     = *(const float4*)&Ip[(size_t)r * N_PAD + cc];
        *(float4*)&Ish[r + 8][cc] = *(const float4*)&Ip[(size_t)(r + 8) * N_PAD + cc];
        __syncthreads();
        #pragma unroll
        for (int dd = 0; dd < BD; dd++) {
            float4 a0 = *(float4*)&Ssh[dd][ty * 4];
            float4 a1 = *(float4*)&Ssh[dd][64 + ty * 4];
            float4 b0 = *(float4*)&Ish[dd][tx * 4];
            float4 b1 = *(float4*)&Ish[dd][64 + tx * 4];
            float av[8] = {a0.x, a0.y, a0.z, a0.w, a1.x, a1.y, a1.z, a1.w};
            float bv[8] = {b0.x, b0.y, b0.z, b0.w, b1.x, b1.y, b1.z, b1.w};
            #pragma unroll
            for (int a = 0; a < 8; a++)
                #pragma unroll
                for (int b = 0; b < 8; b++)
                    acc[a][b] = fmaf(av[a], bv[b], acc[a][b]);
        }
        __syncthreads();
    }

    // epilogue: scale by sinv[j], mask padded j, argmax (first-occurrence tie-break)
    float sj[8]; int jg[8];
    #pragma unroll
    for (int b = 0; b < 8; b++) {
        int jl = (b < 4) ? (tx * 4 + b) : (64 + tx * 4 + (b - 4));
        jg[b] = j0 + jl;
        sj[b] = sinv[jg[b]];
    }

    #pragma unroll
    for (int a = 0; a < 8; a++) {
        float best = -INFINITY; int bidx = 0x7fffffff;
        #pragma unroll
        for (int b = 0; b < 8; b++) {   // jg ascending within thread -> strict '>' keeps smallest j
            float v = (jg[b] < N_REAL) ? acc[a][b] * sj[b] : -INFINITY;
            if (v > best) { best = v; bidx = jg[b]; }
        }
        // reduce across the 16 lanes (same ty, contiguous lanes within a wave)
        for (int off = 1; off < 16; off <<= 1) {
            float ov = __shfl_xor(best, off);
            int   oi = __shfl_xor(bidx, off);
            if (ov > best || (ov == best && oi < bidx)) { best = ov; bidx = oi; }
        }
        if (tx == 0) {
            int i = i0 + ((a < 4) ? (ty * 4 + a) : (64 + ty * 4 + (a - 4)));
            pval[(size_t)blockIdx.y * N_PAD + i] = best;
            pidx[(size_t)blockIdx.y * N_PAD + i] = bidx;
        }
    }
}

// ---------------------------------------------------------------------------
// Merge per-j-tile argmax partials (scan ascending -> first-occurrence semantics)
__global__ void merge_nearest(const float* __restrict__ pval,
                              const int* __restrict__ pidx,
                              int* __restrict__ nearest) {
    int n = blockIdx.x * blockDim.x + threadIdx.x;
    if (n >= N_REAL) return;
    float best = -INFINITY; int bidx = 0x7fffffff;
    for (int jt = 0; jt < JTILES; jt++) {
        float v  = pval[(size_t)jt * N_PAD + n];
        int   id = pidx[(size_t)jt * N_PAD + n];
        if (v > best || (v == best && id < bidx)) { best = v; bidx = id; }
    }
    nearest[n] = bidx;
}

// ---------------------------------------------------------------------------
// loss = mean over (d,n) of (I[d][n] - S[d][nearest[n]])^2
__global__ void loss_kernel(const float* __restrict__ I, const float* __restrict__ S,
                            const int* __restrict__ nearest, double* __restrict__ accum) {
    __shared__ double sh[256];
    const long long total = (long long)D_REAL * N_REAL;
    long long stride = (long long)gridDim.x * blockDim.x;
    double s = 0.0;
    for (long long idx = (long long)blockIdx.x * blockDim.x + threadIdx.x;
         idx < total; idx += stride) {
        int d = (int)(idx / N_REAL);
        int n = (int)(idx - (long long)d * N_REAL);
        float iv = I[(size_t)d * N_PAD + n];
        float sv = S[(size_t)d * N_PAD + nearest[n]];
        float df = iv - sv;
        s += (double)(df * df);
    }
    sh[threadIdx.x] = s;
    __syncthreads();
    for (int w = 128; w > 0; w >>= 1) {
        if ((int)threadIdx.x < w) sh[threadIdx.x] += sh[threadIdx.x + w];
        __syncthreads();
    }
    if (threadIdx.x == 0) atomicAdd(accum, sh[0]);
}

__global__ void finalize(const double* __restrict__ accum, float* __restrict__ out) {
    out[0] = (float)(accum[0] / (double)((long long)D_REAL * N_REAL));
}

// ---------------------------------------------------------------------------
extern "C" void kernel_launch(void* const* d_in, const int* in_sizes, int n_in,
                              void* d_out, int out_size, void* d_ws, size_t ws_size,
                              hipStream_t stream) {
    const float* style_resp = (const float*)d_in[0];
    const float* style_map  = (const float*)d_in[1];
    const float* output_map = (const float*)d_in[2];
    const float* model_resp = (const float*)d_in[3];
    float* out = (float*)d_out;

    // workspace layout (floats): S | I | norm2/sinv | pval | pidx | nearest | accum
    float* S       = (float*)d_ws;
    float* I       = S + (size_t)D_PAD * N_PAD;
    float* norm2   = I + (size_t)D_PAD * N_PAD;
    float* pval    = norm2 + N_PAD;
    int*   pidx    = (int*)(pval + (size_t)JTILES * N_PAD);
    int*   nearest = pidx + (size_t)JTILES * N_PAD;
    double* accum  = (double*)(nearest + N_PAD);   // byte offset divisible by 8

    zero_ws<<<(N_PAD + 255) / 256, 256, 0, stream>>>(norm2, accum);

    int total   = D_PAD * N_PAD;
    int bblocks = (total + 255) / 256;
    build_patches<<<bblocks, 256, 0, stream>>>(style_resp, style_map, S);
    build_patches<<<bblocks, 256, 0, stream>>>(model_resp, output_map, I);

    norm_partial<<<dim3((N_PAD + 255) / 256, 9), 256, 0, stream>>>(S, norm2);
    norm_fin<<<(N_PAD + 255) / 256, 256, 0, stream>>>(norm2);

    gemm_argmax<<<dim3(ITILES, JTILES), 256, 0, stream>>>(S, I, norm2, pval, pidx);

    merge_nearest<<<(N_REAL + 255) / 256, 256, 0, stream>>>(pval, pidx, nearest);

    loss_kernel<<<2048, 256, 0, stream>>>(I, S, nearest, accum);
    finalize<<<1, 1, 0, stream>>>(accum, out);
}

// Round 2
// 718.306 us; speedup vs baseline: 4.1541x; 4.1541x over previous
//
#include <hip/hip_runtime.h>
#include <float.h>
#include <math.h>

// Problem constants
#define D_REAL 2331   // 259 channels * 3*3 patch
#define D_PAD  2336   // multiple of 32 (MFMA K-tile)
#define N_REAL 7225   // 85*85 patches
#define N_PAD  7296   // 57*128
#define JTILES 57
#define ITILES 57

typedef __attribute__((ext_vector_type(8))) short bf16x8_t;  // 8 bf16 = 4 VGPRs
typedef __attribute__((ext_vector_type(4))) float f32x4_t;   // MFMA C/D

__device__ __forceinline__ unsigned short f2bf(float x) {
    union { float f; unsigned int u; } v; v.f = x;
    unsigned int r = v.u + 0x7FFFu + ((v.u >> 16) & 1u);   // RNE
    return (unsigned short)(r >> 16);
}
__device__ __forceinline__ float bf2f(unsigned short b) {
    union { unsigned int u; float f; } v; v.u = ((unsigned int)b) << 16;
    return v.f;
}

#define GLOAD_LDS16(g, l) __builtin_amdgcn_global_load_lds( \
    (const __attribute__((address_space(1))) void*)(g),     \
    (__attribute__((address_space(3))) void*)(l), 16, 0, 0)

// ---------------------------------------------------------------------------
__global__ void init_accum(double* __restrict__ accum) {
    if (threadIdx.x == 0) *accum = 0.0;
}

// ---------------------------------------------------------------------------
// Build TRANSPOSED bf16 patch matrix Pb[N_PAD][D_PAD]: Pb[n][d] = patch value.
// d = c*9 + p*3 + q ; n = u*85 + v ; value = sr[c][3u+p][3v+q] with the map
// channels = 50 * avgpool4(map). 32x32 tile via LDS: coalesced-ish reads over
// n, coalesced writes over d.
__global__ __launch_bounds__(256) void build_patches_t(
        const float* __restrict__ resp, const float* __restrict__ map,
        unsigned short* __restrict__ Pb) {
    __shared__ unsigned short t[32][33];
    const int n0 = blockIdx.x * 32, d0 = blockIdx.y * 32;
    const int c32 = threadIdx.x & 31, r8 = threadIdx.x >> 5;
    #pragma unroll
    for (int k = 0; k < 4; k++) {
        int r = r8 + k * 8;          // d-local
        int d = d0 + r, n = n0 + c32;
        float val = 0.f;
        if (d < D_REAL && n < N_REAL) {
            int c = d / 9, rr = d - c * 9;
            int p = rr / 3, q = rr - p * 3;
            int u = n / 85, v = n - u * 85;
            int row = 3 * u + p, col = 3 * v + q;
            if (c < 256) {
                val = resp[((size_t)c << 16) + ((size_t)row << 8) + col];
            } else {
                const float* mp = map + ((size_t)(c - 256) << 20)
                                      + ((size_t)(row * 4) << 10) + (size_t)(col * 4);
                float s = 0.f;
                #pragma unroll
                for (int a = 0; a < 4; a++)
                    #pragma unroll
                    for (int b = 0; b < 4; b++) s += mp[a * 1024 + b];
                val = 3.125f * s;    // 50 * (1/16)
            }
        }
        t[r][c32] = f2bf(val);
    }
    __syncthreads();
    #pragma unroll
    for (int k = 0; k < 4; k++) {
        int nr = r8 + k * 8;         // n-local
        Pb[(size_t)(n0 + nr) * D_PAD + d0 + c32] = t[c32][nr];
    }
}

// ---------------------------------------------------------------------------
// sinv[n] = 1/||S[:,n]|| from bf16 Sb (one wave per column; padded d are 0).
__global__ __launch_bounds__(256) void col_norms(const unsigned short* __restrict__ Sb,
                                                 float* __restrict__ sinv) {
    int n = blockIdx.x * 4 + (threadIdx.x >> 6);
    int lane = threadIdx.x & 63;
    if (n >= N_PAD) return;
    const unsigned short* sp = Sb + (size_t)n * D_PAD;
    float s = 0.f;
    for (int d = lane; d < D_PAD; d += 64) {
        float v = bf2f(sp[d]);
        s = fmaf(v, v, s);
    }
    #pragma unroll
    for (int off = 32; off > 0; off >>= 1) s += __shfl_xor(s, off);
    if (lane == 0) sinv[n] = (n < N_REAL) ? rsqrtf(s) : 0.f;
}

// ---------------------------------------------------------------------------
// MFMA GEMM + fused per-row argmax. sim[i][j] = dot(S[:,i],I[:,j]) * sinv[j].
// A = Sb (rows i, K-contig), B = Ib (rows j, K-contig) -> NT GEMM.
// 128x128 tile, BK=32, 4 waves in 2x2, each wave 4x4 MFMA 16x16x32.
__global__ __launch_bounds__(256) void gemm_argmax(
        const unsigned short* __restrict__ Sb, const unsigned short* __restrict__ Ib,
        const float* __restrict__ sinv,
        float* __restrict__ pval, int* __restrict__ pidx) {
    __shared__ __align__(16) unsigned short Ash[128][32];
    __shared__ __align__(16) unsigned short Bsh[128][32];
    const int tid = threadIdx.x;
    const int L = tid & 63, w = tid >> 6;
    const int i0 = blockIdx.x * 128, j0 = blockIdx.y * 128;
    const int m = L & 15, q = L >> 4;              // frag lane coords
    const int wi = (w >> 1) * 64, wj = (w & 1) * 64;

    f32x4_t acc[4][4];
    #pragma unroll
    for (int a = 0; a < 4; a++)
        #pragma unroll
        for (int b = 0; b < 4; b++) acc[a][b] = (f32x4_t){0.f, 0.f, 0.f, 0.f};

    // staging: wave w loads 32 rows of A and 32 rows of B per K-step,
    // 2 global_load_lds (1 KB each = 16 rows x 64 B) per matrix.
    // lane L -> row (L>>2), 16B-chunk (L&3). LDS dest = base + L*16 (HW).
    const unsigned short* ga0 = Sb + (size_t)(i0 + w * 32 + (L >> 2)) * D_PAD + ((L & 3) << 3);
    const unsigned short* ga1 = ga0 + (size_t)16 * D_PAD;
    const unsigned short* gb0 = Ib + (size_t)(j0 + w * 32 + (L >> 2)) * D_PAD + ((L & 3) << 3);
    const unsigned short* gb1 = gb0 + (size_t)16 * D_PAD;
    unsigned short* lA0 = &Ash[w * 32][0];
    unsigned short* lA1 = &Ash[w * 32 + 16][0];
    unsigned short* lB0 = &Bsh[w * 32][0];
    unsigned short* lB1 = &Bsh[w * 32 + 16][0];

    for (int d0 = 0; d0 < D_PAD; d0 += 32) {
        __syncthreads();                       // prev tile fully consumed
        GLOAD_LDS16(ga0, lA0);
        GLOAD_LDS16(ga1, lA1);
        GLOAD_LDS16(gb0, lB0);
        GLOAD_LDS16(gb1, lB1);
        ga0 += 32; ga1 += 32; gb0 += 32; gb1 += 32;
        __syncthreads();                       // vmcnt drained: tile visible

        bf16x8_t af[4], bfr[4];
        #pragma unroll
        for (int mi = 0; mi < 4; mi++)
            af[mi] = *(const bf16x8_t*)&Ash[wi + mi * 16 + m][q * 8];
        #pragma unroll
        for (int nj = 0; nj < 4; nj++)
            bfr[nj] = *(const bf16x8_t*)&Bsh[wj + nj * 16 + m][q * 8];
        #pragma unroll
        for (int mi = 0; mi < 4; mi++)
            #pragma unroll
            for (int nj = 0; nj < 4; nj++)
                acc[mi][nj] = __builtin_amdgcn_mfma_f32_16x16x32_bf16(
                    af[mi], bfr[nj], acc[mi][nj], 0, 0, 0);
    }

    // Epilogue. C/D layout: col = lane&15 (=m, j-dir), row = q*4 + reg (i-dir).
    float sjv[4];
    #pragma unroll
    for (int nj = 0; nj < 4; nj++) {
        int j = j0 + wj + nj * 16 + m;
        sjv[nj] = sinv[j];                     // 0 for padded j (harmless; masked below)
    }
    #pragma unroll
    for (int mi = 0; mi < 4; mi++) {
        #pragma unroll
        for (int r = 0; r < 4; r++) {
            float best = -INFINITY; int bidx = 0x7fffffff;
            #pragma unroll
            for (int nj = 0; nj < 4; nj++) {   // j ascending in nj -> '>' keeps smallest
                int j = j0 + wj + nj * 16 + m;
                float v = (j < N_REAL) ? acc[mi][nj][r] * sjv[nj] : -INFINITY;
                if (v > best) { best = v; bidx = j; }
            }
            // reduce across the 16 lanes sharing this i (same q group)
            #pragma unroll
            for (int off = 1; off < 16; off <<= 1) {
                float ov = __shfl_xor(best, off);
                int   oi = __shfl_xor(bidx, off);
                if (ov > best || (ov == best && oi < bidx)) { best = ov; bidx = oi; }
            }
            if (m == 0) {
                int i = i0 + wi + mi * 16 + q * 4 + r;
                pval[(size_t)blockIdx.y * N_PAD + i] = best;
                pidx[(size_t)blockIdx.y * N_PAD + i] = bidx;
            }
        }
    }
}

// ---------------------------------------------------------------------------
__global__ void merge_nearest(const float* __restrict__ pval,
                              const int* __restrict__ pidx,
                              int* __restrict__ nearest) {
    int n = blockIdx.x * blockDim.x + threadIdx.x;
    if (n >= N_REAL) return;
    float best = -INFINITY; int bidx = 0x7fffffff;
    for (int jt = 0; jt < JTILES; jt++) {
        float v  = pval[(size_t)jt * N_PAD + n];
        int   id = pidx[(size_t)jt * N_PAD + n];
        if (v > best || (v == best && id < bidx)) { best = v; bidx = id; }
    }
    nearest[n] = bidx;
}

// ---------------------------------------------------------------------------
// loss = mean((I - S[:,nearest])^2) over d<D_REAL, n<N_REAL. Transposed bf16
// layout: one block per n, threads over d -> both reads contiguous.
__global__ __launch_bounds__(256) void loss_kernel(
        const unsigned short* __restrict__ Ib, const unsigned short* __restrict__ Sb,
        const int* __restrict__ nearest, double* __restrict__ accum) {
    __shared__ float wsum[4];
    int n = blockIdx.x;
    int jn = nearest[n];
    const unsigned short* ip = Ib + (size_t)n  * D_PAD;
    const unsigned short* sp = Sb + (size_t)jn * D_PAD;
    float s = 0.f;
    for (int d = threadIdx.x; d < D_REAL; d += 256) {
        float df = bf2f(ip[d]) - bf2f(sp[d]);
        s = fmaf(df, df, s);
    }
    #pragma unroll
    for (int off = 32; off > 0; off >>= 1) s += __shfl_xor(s, off);
    int lane = threadIdx.x & 63, wv = threadIdx.x >> 6;
    if (lane == 0) wsum[wv] = s;
    __syncthreads();
    if (threadIdx.x == 0) {
        double t = (double)wsum[0] + (double)wsum[1] + (double)wsum[2] + (double)wsum[3];
        atomicAdd(accum, t);
    }
}

__global__ void finalize(const double* __restrict__ accum, float* __restrict__ out) {
    out[0] = (float)(accum[0] / (double)((long long)D_REAL * N_REAL));
}

// ---------------------------------------------------------------------------
extern "C" void kernel_launch(void* const* d_in, const int* in_sizes, int n_in,
                              void* d_out, int out_size, void* d_ws, size_t ws_size,
                              hipStream_t stream) {
    const float* style_resp = (const float*)d_in[0];
    const float* style_map  = (const float*)d_in[1];
    const float* output_map = (const float*)d_in[2];
    const float* model_resp = (const float*)d_in[3];
    float* out = (float*)d_out;

    // workspace (≈72 MB): Sb | Ib (bf16, transposed) | sinv | pval | pidx | nearest | accum
    unsigned short* Sb = (unsigned short*)d_ws;
    unsigned short* Ib = Sb + (size_t)D_PAD * N_PAD;
    float* sinv    = (float*)(Ib + (size_t)D_PAD * N_PAD);
    float* pval    = sinv + N_PAD;
    int*   pidx    = (int*)(pval + (size_t)JTILES * N_PAD);
    int*   nearest = pidx + (size_t)JTILES * N_PAD;
    double* accum  = (double*)(nearest + N_PAD);

    init_accum<<<1, 64, 0, stream>>>(accum);

    dim3 bgrid(N_PAD / 32, D_PAD / 32);   // 228 x 73
    build_patches_t<<<bgrid, 256, 0, stream>>>(style_resp, style_map, Sb);
    build_patches_t<<<bgrid, 256, 0, stream>>>(model_resp, output_map, Ib);

    col_norms<<<N_PAD / 4, 256, 0, stream>>>(Sb, sinv);

    gemm_argmax<<<dim3(ITILES, JTILES), 256, 0, stream>>>(Sb, Ib, sinv, pval, pidx);

    merge_nearest<<<(N_REAL + 255) / 256, 256, 0, stream>>>(pval, pidx, nearest);

    loss_kernel<<<N_REAL, 256, 0, stream>>>(Ib, Sb, nearest, accum);
    finalize<<<1, 1, 0, stream>>>(accum, out);
}

// Round 3
// 702.014 us; speedup vs baseline: 4.2505x; 1.0232x over previous
//
#include <hip/hip_runtime.h>
#include <float.h>
#include <math.h>

// Problem constants
#define D_REAL 2331   // 259 channels * 3*3 patch
#define D_PAD  2336   // multiple of 32 (MFMA K-tile); 292 16B-chunks
#define N_REAL 7225   // 85*85 patches
#define N_PAD  7296   // 57*128
#define JTILES 57
#define ITILES 57

typedef __attribute__((ext_vector_type(8))) short bf16x8_t;  // 8 bf16 = 4 VGPRs
typedef __attribute__((ext_vector_type(4))) float f32x4_t;   // MFMA C/D

__device__ __forceinline__ unsigned short f2bf(float x) {
    union { float f; unsigned int u; } v; v.f = x;
    unsigned int r = v.u + 0x7FFFu + ((v.u >> 16) & 1u);   // RNE
    return (unsigned short)(r >> 16);
}
__device__ __forceinline__ float bflo(unsigned int u) {
    union { unsigned int x; float f; } v; v.x = u << 16; return v.f;
}
__device__ __forceinline__ float bfhi(unsigned int u) {
    union { unsigned int x; float f; } v; v.x = u & 0xFFFF0000u; return v.f;
}

#define GLOAD_LDS16(g, l) __builtin_amdgcn_global_load_lds( \
    (const __attribute__((address_space(1))) void*)(g),     \
    (__attribute__((address_space(3))) void*)(l), 16, 0, 0)

// ---------------------------------------------------------------------------
__global__ void init_accum(double* __restrict__ accum) {
    if (threadIdx.x == 0) *accum = 0.0;
}

// ---------------------------------------------------------------------------
// Build TRANSPOSED bf16 patch matrix Pb[N_PAD][D_PAD]: Pb[n][d] = patch value.
__global__ __launch_bounds__(256) void build_patches_t(
        const float* __restrict__ resp, const float* __restrict__ map,
        unsigned short* __restrict__ Pb) {
    __shared__ unsigned short t[32][33];
    const int n0 = blockIdx.x * 32, d0 = blockIdx.y * 32;
    const int c32 = threadIdx.x & 31, r8 = threadIdx.x >> 5;
    #pragma unroll
    for (int k = 0; k < 4; k++) {
        int r = r8 + k * 8;          // d-local
        int d = d0 + r, n = n0 + c32;
        float val = 0.f;
        if (d < D_REAL && n < N_REAL) {
            int c = d / 9, rr = d - c * 9;
            int p = rr / 3, q = rr - p * 3;
            int u = n / 85, v = n - u * 85;
            int row = 3 * u + p, col = 3 * v + q;
            if (c < 256) {
                val = resp[((size_t)c << 16) + ((size_t)row << 8) + col];
            } else {
                const float* mp = map + ((size_t)(c - 256) << 20)
                                      + ((size_t)(row * 4) << 10) + (size_t)(col * 4);
                float s = 0.f;
                #pragma unroll
                for (int a = 0; a < 4; a++)
                    #pragma unroll
                    for (int b = 0; b < 4; b++) s += mp[a * 1024 + b];
                val = 3.125f * s;    // 50 * (1/16)
            }
        }
        t[r][c32] = f2bf(val);
    }
    __syncthreads();
    #pragma unroll
    for (int k = 0; k < 4; k++) {
        int nr = r8 + k * 8;         // n-local
        Pb[(size_t)(n0 + nr) * D_PAD + d0 + c32] = t[c32][nr];
    }
}

// ---------------------------------------------------------------------------
// sinv[n] = 1/||S[:,n]||, vectorized 16B loads (d-pad is zero -> exact).
__global__ __launch_bounds__(256) void col_norms(const unsigned short* __restrict__ Sb,
                                                 float* __restrict__ sinv) {
    int n = blockIdx.x * 4 + (threadIdx.x >> 6);
    int lane = threadIdx.x & 63;
    const uint4* sp = (const uint4*)(Sb + (size_t)n * D_PAD);
    float s = 0.f;
    for (int k = lane; k < D_PAD / 8; k += 64) {
        uint4 a = sp[k];
        float x0 = bflo(a.x), x1 = bfhi(a.x), x2 = bflo(a.y), x3 = bfhi(a.y);
        float x4 = bflo(a.z), x5 = bfhi(a.z), x6 = bflo(a.w), x7 = bfhi(a.w);
        s = fmaf(x0, x0, s); s = fmaf(x1, x1, s);
        s = fmaf(x2, x2, s); s = fmaf(x3, x3, s);
        s = fmaf(x4, x4, s); s = fmaf(x5, x5, s);
        s = fmaf(x6, x6, s); s = fmaf(x7, x7, s);
    }
    #pragma unroll
    for (int off = 32; off > 0; off >>= 1) s += __shfl_xor(s, off);
    if (lane == 0) sinv[n] = (n < N_REAL) ? rsqrtf(s) : 0.f;
}

// ---------------------------------------------------------------------------
// MFMA GEMM + fused per-row argmax, XOR-swizzled LDS to kill bank conflicts.
// Swizzle: 16B chunk c of row r is stored at chunk position c ^ ((r>>1)&3).
// Store side picks the source chunk per lane (global_load_lds writes lane L
// at LDS base + 16L, fixed by HW); read side XORs the chunk index. Bank
// groups (row&1, chunk') then cover all 8 4-bank groups with 2 lanes each ->
// 2-way aliasing = free (vs 8-way before).
__global__ __launch_bounds__(256) void gemm_argmax(
        const unsigned short* __restrict__ Sb, const unsigned short* __restrict__ Ib,
        const float* __restrict__ sinv,
        float* __restrict__ pval, int* __restrict__ pidx) {
    __shared__ __align__(16) unsigned short Ash[128][32];
    __shared__ __align__(16) unsigned short Bsh[128][32];
    const int tid = threadIdx.x;
    const int L = tid & 63, w = tid >> 6;
    const int i0 = blockIdx.x * 128, j0 = blockIdx.y * 128;
    const int m = L & 15, q = L >> 4;              // frag lane coords
    const int wi = (w >> 1) * 64, wj = (w & 1) * 64;

    f32x4_t acc[4][4];
    #pragma unroll
    for (int a = 0; a < 4; a++)
        #pragma unroll
        for (int b = 0; b < 4; b++) acc[a][b] = (f32x4_t){0.f, 0.f, 0.f, 0.f};

    // staging: lane L covers LDS row_local rl = L>>2, chunk position L&3;
    // fetch global chunk ck = (L&3) ^ ((rl>>1)&3)  (XOR involution).
    const int rl = L >> 2;
    const int ck = (L & 3) ^ ((rl >> 1) & 3);
    const unsigned short* ga0 = Sb + (size_t)(i0 + w * 32 + rl) * D_PAD + (ck << 3);
    const unsigned short* ga1 = ga0 + (size_t)16 * D_PAD;
    const unsigned short* gb0 = Ib + (size_t)(j0 + w * 32 + rl) * D_PAD + (ck << 3);
    const unsigned short* gb1 = gb0 + (size_t)16 * D_PAD;
    unsigned short* lA0 = &Ash[w * 32][0];
    unsigned short* lA1 = &Ash[w * 32 + 16][0];
    unsigned short* lB0 = &Bsh[w * 32][0];
    unsigned short* lB1 = &Bsh[w * 32 + 16][0];

    // read-side swizzled chunk (row = 16*a + m -> (row>>1)&3 == (m>>1)&3)
    const int ch = (q ^ ((m >> 1) & 3)) << 3;

    for (int d0 = 0; d0 < D_PAD; d0 += 32) {
        __syncthreads();                       // prev tile fully consumed
        GLOAD_LDS16(ga0, lA0);
        GLOAD_LDS16(ga1, lA1);
        GLOAD_LDS16(gb0, lB0);
        GLOAD_LDS16(gb1, lB1);
        ga0 += 32; ga1 += 32; gb0 += 32; gb1 += 32;
        __syncthreads();                       // vmcnt drained: tile visible

        bf16x8_t af[4], bfr[4];
        #pragma unroll
        for (int mi = 0; mi < 4; mi++)
            af[mi] = *(const bf16x8_t*)&Ash[wi + mi * 16 + m][ch];
        #pragma unroll
        for (int nj = 0; nj < 4; nj++)
            bfr[nj] = *(const bf16x8_t*)&Bsh[wj + nj * 16 + m][ch];
        #pragma unroll
        for (int mi = 0; mi < 4; mi++)
            #pragma unroll
            for (int nj = 0; nj < 4; nj++)
                acc[mi][nj] = __builtin_amdgcn_mfma_f32_16x16x32_bf16(
                    af[mi], bfr[nj], acc[mi][nj], 0, 0, 0);
    }

    // Epilogue. C/D layout: col = lane&15 (=m, j-dir), row = q*4 + reg (i-dir).
    float sjv[4];
    #pragma unroll
    for (int nj = 0; nj < 4; nj++) {
        int j = j0 + wj + nj * 16 + m;
        sjv[nj] = sinv[j];
    }
    #pragma unroll
    for (int mi = 0; mi < 4; mi++) {
        #pragma unroll
        for (int r = 0; r < 4; r++) {
            float best = -INFINITY; int bidx = 0x7fffffff;
            #pragma unroll
            for (int nj = 0; nj < 4; nj++) {   // j ascending -> '>' keeps smallest
                int j = j0 + wj + nj * 16 + m;
                float v = (j < N_REAL) ? acc[mi][nj][r] * sjv[nj] : -INFINITY;
                if (v > best) { best = v; bidx = j; }
            }
            #pragma unroll
            for (int off = 1; off < 16; off <<= 1) {
                float ov = __shfl_xor(best, off);
                int   oi = __shfl_xor(bidx, off);
                if (ov > best || (ov == best && oi < bidx)) { best = ov; bidx = oi; }
            }
            if (m == 0) {
                int i = i0 + wi + mi * 16 + q * 4 + r;
                pval[(size_t)blockIdx.y * N_PAD + i] = best;
                pidx[(size_t)blockIdx.y * N_PAD + i] = bidx;
            }
        }
    }
}

// ---------------------------------------------------------------------------
__global__ void merge_nearest(const float* __restrict__ pval,
                              const int* __restrict__ pidx,
                              int* __restrict__ nearest) {
    int n = blockIdx.x * blockDim.x + threadIdx.x;
    if (n >= N_REAL) return;
    float best = -INFINITY; int bidx = 0x7fffffff;
    for (int jt = 0; jt < JTILES; jt++) {
        float v  = pval[(size_t)jt * N_PAD + n];
        int   id = pidx[(size_t)jt * N_PAD + n];
        if (v > best || (v == best && id < bidx)) { best = v; bidx = id; }
    }
    nearest[n] = bidx;
}

// ---------------------------------------------------------------------------
// loss = mean((I - S[:,nearest])^2); 16B vector loads (d-pad zero -> exact).
__global__ __launch_bounds__(256) void loss_kernel(
        const unsigned short* __restrict__ Ib, const unsigned short* __restrict__ Sb,
        const int* __restrict__ nearest, double* __restrict__ accum) {
    __shared__ float wsum[4];
    int n = blockIdx.x;
    int jn = nearest[n];
    const uint4* ip = (const uint4*)(Ib + (size_t)n  * D_PAD);
    const uint4* sp = (const uint4*)(Sb + (size_t)jn * D_PAD);
    float s = 0.f;
    for (int k = threadIdx.x; k < D_PAD / 8; k += 256) {
        uint4 a = ip[k], b = sp[k];
        float d0 = bflo(a.x) - bflo(b.x), d1 = bfhi(a.x) - bfhi(b.x);
        float d2 = bflo(a.y) - bflo(b.y), d3 = bfhi(a.y) - bfhi(b.y);
        float d4 = bflo(a.z) - bflo(b.z), d5 = bfhi(a.z) - bfhi(b.z);
        float d6 = bflo(a.w) - bflo(b.w), d7 = bfhi(a.w) - bfhi(b.w);
        s = fmaf(d0, d0, s); s = fmaf(d1, d1, s);
        s = fmaf(d2, d2, s); s = fmaf(d3, d3, s);
        s = fmaf(d4, d4, s); s = fmaf(d5, d5, s);
        s = fmaf(d6, d6, s); s = fmaf(d7, d7, s);
    }
    #pragma unroll
    for (int off = 32; off > 0; off >>= 1) s += __shfl_xor(s, off);
    int lane = threadIdx.x & 63, wv = threadIdx.x >> 6;
    if (lane == 0) wsum[wv] = s;
    __syncthreads();
    if (threadIdx.x == 0) {
        double t = (double)wsum[0] + (double)wsum[1] + (double)wsum[2] + (double)wsum[3];
        atomicAdd(accum, t);
    }
}

__global__ void finalize(const double* __restrict__ accum, float* __restrict__ out) {
    out[0] = (float)(accum[0] / (double)((long long)D_REAL * N_REAL));
}

// ---------------------------------------------------------------------------
extern "C" void kernel_launch(void* const* d_in, const int* in_sizes, int n_in,
                              void* d_out, int out_size, void* d_ws, size_t ws_size,
                              hipStream_t stream) {
    const float* style_resp = (const float*)d_in[0];
    const float* style_map  = (const float*)d_in[1];
    const float* output_map = (const float*)d_in[2];
    const float* model_resp = (const float*)d_in[3];
    float* out = (float*)d_out;

    // workspace (~72 MB): Sb | Ib (bf16, transposed) | sinv | pval | pidx | nearest | accum
    unsigned short* Sb = (unsigned short*)d_ws;
    unsigned short* Ib = Sb + (size_t)D_PAD * N_PAD;
    float* sinv    = (float*)(Ib + (size_t)D_PAD * N_PAD);
    float* pval    = sinv + N_PAD;
    int*   pidx    = (int*)(pval + (size_t)JTILES * N_PAD);
    int*   nearest = pidx + (size_t)JTILES * N_PAD;
    double* accum  = (double*)(nearest + N_PAD);

    init_accum<<<1, 64, 0, stream>>>(accum);

    dim3 bgrid(N_PAD / 32, D_PAD / 32);   // 228 x 73
    build_patches_t<<<bgrid, 256, 0, stream>>>(style_resp, style_map, Sb);
    build_patches_t<<<bgrid, 256, 0, stream>>>(model_resp, output_map, Ib);

    col_norms<<<N_PAD / 4, 256, 0, stream>>>(Sb, sinv);

    gemm_argmax<<<dim3(ITILES, JTILES), 256, 0, stream>>>(Sb, Ib, sinv, pval, pidx);

    merge_nearest<<<(N_REAL + 255) / 256, 256, 0, stream>>>(pval, pidx, nearest);

    loss_kernel<<<N_REAL, 256, 0, stream>>>(Ib, Sb, nearest, accum);
    finalize<<<1, 1, 0, stream>>>(accum, out);
}

// Round 4
// 670.892 us; speedup vs baseline: 4.4477x; 1.0464x over previous
//
#include <hip/hip_runtime.h>
#include <float.h>
#include <math.h>

// Problem constants
#define D_REAL 2331   // 259 channels * 3*3 patch
#define D_PAD  2336   // multiple of 32 (MFMA K-tile)
#define N_REAL 7225   // 85*85 patches
#define N_PAD  7296   // 57*128
#define JTILES 57
#define ITILES 57
#define STILES 15     // ceil(57/4) supertile grid per dim

typedef __attribute__((ext_vector_type(8))) short bf16x8_t;  // 8 bf16 = 4 VGPRs
typedef __attribute__((ext_vector_type(4))) float f32x4_t;   // MFMA C/D

__device__ __forceinline__ unsigned short f2bf(float x) {
    union { float f; unsigned int u; } v; v.f = x;
    unsigned int r = v.u + 0x7FFFu + ((v.u >> 16) & 1u);   // RNE
    return (unsigned short)(r >> 16);
}
__device__ __forceinline__ float bflo(unsigned int u) {
    union { unsigned int x; float f; } v; v.x = u << 16; return v.f;
}
__device__ __forceinline__ float bfhi(unsigned int u) {
    union { unsigned int x; float f; } v; v.x = u & 0xFFFF0000u; return v.f;
}

#define GLOAD_LDS16(g, l) __builtin_amdgcn_global_load_lds( \
    (const __attribute__((address_space(1))) void*)(g),     \
    (__attribute__((address_space(3))) void*)(l), 16, 0, 0)

// ---------------------------------------------------------------------------
// Resp part of Pb[n][d] (d < 2304). Block = (u-row, 32-d tile).
// Coalesced slab load: channels c0..c0+cN-1, rows 3u..3u+2, cols 0..255.
__global__ __launch_bounds__(256) void build_resp(
        const float* __restrict__ resp, unsigned short* __restrict__ Pb) {
    __shared__ float slab[5 * 768];            // [cc][rr][col], 15 KB max
    const int u  = blockIdx.x;                 // 0..84
    const int d0 = blockIdx.y * 32;            // 0..2272
    const int c0 = d0 / 9;
    const int cN = (d0 + 31) / 9 - c0 + 1;     // <= 5
    const int total = cN * 768;
    for (int idx = threadIdx.x; idx < total; idx += 256) {
        int cc = idx / 768;
        int rem = idx - cc * 768;              // (row-3u)*256 + col
        slab[idx] = resp[(((size_t)(c0 + cc)) << 16) + ((size_t)(3 * u) << 8) + rem];
    }
    __syncthreads();
    const int dl = threadIdx.x & 31;
    const int d = d0 + dl;
    const int c = d / 9, r9 = d - c * 9, p = r9 / 3, q = r9 - p * 3;
    const int base = (c - c0) * 768 + p * 256 + q;
    const int v0 = threadIdx.x >> 5;           // 0..7
    size_t out = (size_t)(u * 85) * D_PAD + d0 + dl;
    for (int v = v0; v < 85; v += 8)
        Pb[out + (size_t)v * D_PAD] = f2bf(slab[base + 3 * v]);
}

// ---------------------------------------------------------------------------
// Map part: d in [2304, 2336): 27 real map rows (50 * avgpool4) + 5 zero pad.
// Thread t -> n = t>>5, dm = t&31; writes 64B-coalesced over dm.
__global__ __launch_bounds__(256) void build_map(
        const float* __restrict__ map, unsigned short* __restrict__ Pb) {
    int t = blockIdx.x * 256 + threadIdx.x;
    int n = t >> 5, dm = t & 31;
    if (n >= N_REAL) return;
    float val = 0.f;
    if (dm < 27) {
        int u = n / 85, v = n - u * 85;
        int ch = dm / 9, r9 = dm - ch * 9, p = r9 / 3, q = r9 - p * 3;
        const float* mp = map + ((size_t)ch << 20)
                              + ((size_t)((3 * u + p) * 4) << 10)
                              + (size_t)((3 * v + q) * 4);
        float s = 0.f;
        #pragma unroll
        for (int a = 0; a < 4; a++)
            #pragma unroll
            for (int b = 0; b < 4; b++) s += mp[a * 1024 + b];
        val = 3.125f * s;                      // 50 * (1/16)
    }
    Pb[(size_t)n * D_PAD + 2304 + dm] = f2bf(val);
}

// ---------------------------------------------------------------------------
// sinv[n] = 1/||S[:,n]||, 16B vector loads (d-pad zero -> exact).
__global__ __launch_bounds__(256) void col_norms(const unsigned short* __restrict__ Sb,
                                                 float* __restrict__ sinv) {
    int n = blockIdx.x * 4 + (threadIdx.x >> 6);
    int lane = threadIdx.x & 63;
    const uint4* sp = (const uint4*)(Sb + (size_t)n * D_PAD);
    float s = 0.f;
    for (int k = lane; k < D_PAD / 8; k += 64) {
        uint4 a = sp[k];
        float x0 = bflo(a.x), x1 = bfhi(a.x), x2 = bflo(a.y), x3 = bfhi(a.y);
        float x4 = bflo(a.z), x5 = bfhi(a.z), x6 = bflo(a.w), x7 = bfhi(a.w);
        s = fmaf(x0, x0, s); s = fmaf(x1, x1, s);
        s = fmaf(x2, x2, s); s = fmaf(x3, x3, s);
        s = fmaf(x4, x4, s); s = fmaf(x5, x5, s);
        s = fmaf(x6, x6, s); s = fmaf(x7, x7, s);
    }
    #pragma unroll
    for (int off = 32; off > 0; off >>= 1) s += __shfl_xor(s, off);
    if (lane == 0) sinv[n] = (n < N_REAL) ? rsqrtf(s) : 0.f;
}

// ---------------------------------------------------------------------------
// MFMA GEMM + fused argmax. XOR-swizzled LDS (conflict-free), plus 4x4
// supertile block swizzle for per-XCD L2 panel reuse: 8 consecutive linear
// blocks (one round-robin XCD sweep) sit inside one supertile, so each XCD's
// resident window reuses 8 panels 4x out of its own L2 instead of streaming
// ~60 panels from LLC.
__global__ __launch_bounds__(256) void gemm_argmax(
        const unsigned short* __restrict__ Sb, const unsigned short* __restrict__ Ib,
        const float* __restrict__ sinv,
        float* __restrict__ pval, int* __restrict__ pidx) {
    // supertile swizzle over a padded 60x60 tile grid
    const int lb = blockIdx.x;
    const int sup = lb >> 4, win = lb & 15;
    const int it = (sup / STILES) * 4 + (win & 3);
    const int jt = (sup % STILES) * 4 + (win >> 2);
    if (it >= ITILES || jt >= JTILES) return;   // uniform per block: no barrier executed
    const int i0 = it * 128, j0 = jt * 128;

    __shared__ __align__(16) unsigned short Ash[128][32];
    __shared__ __align__(16) unsigned short Bsh[128][32];
    const int tid = threadIdx.x;
    const int L = tid & 63, w = tid >> 6;
    const int m = L & 15, q = L >> 4;
    const int wi = (w >> 1) * 64, wj = (w & 1) * 64;

    f32x4_t acc[4][4];
    #pragma unroll
    for (int a = 0; a < 4; a++)
        #pragma unroll
        for (int b = 0; b < 4; b++) acc[a][b] = (f32x4_t){0.f, 0.f, 0.f, 0.f};

    // staging: lane L -> LDS row rl=L>>2, chunk pos L&3; global chunk XOR-swizzled
    const int rl = L >> 2;
    const int ck = (L & 3) ^ ((rl >> 1) & 3);
    const unsigned short* ga0 = Sb + (size_t)(i0 + w * 32 + rl) * D_PAD + (ck << 3);
    const unsigned short* ga1 = ga0 + (size_t)16 * D_PAD;
    const unsigned short* gb0 = Ib + (size_t)(j0 + w * 32 + rl) * D_PAD + (ck << 3);
    const unsigned short* gb1 = gb0 + (size_t)16 * D_PAD;
    unsigned short* lA0 = &Ash[w * 32][0];
    unsigned short* lA1 = &Ash[w * 32 + 16][0];
    unsigned short* lB0 = &Bsh[w * 32][0];
    unsigned short* lB1 = &Bsh[w * 32 + 16][0];

    const int ch = (q ^ ((m >> 1) & 3)) << 3;   // read-side swizzled chunk

    for (int d0 = 0; d0 < D_PAD; d0 += 32) {
        __syncthreads();
        GLOAD_LDS16(ga0, lA0);
        GLOAD_LDS16(ga1, lA1);
        GLOAD_LDS16(gb0, lB0);
        GLOAD_LDS16(gb1, lB1);
        ga0 += 32; ga1 += 32; gb0 += 32; gb1 += 32;
        __syncthreads();

        bf16x8_t af[4], bfr[4];
        #pragma unroll
        for (int mi = 0; mi < 4; mi++)
            af[mi] = *(const bf16x8_t*)&Ash[wi + mi * 16 + m][ch];
        #pragma unroll
        for (int nj = 0; nj < 4; nj++)
            bfr[nj] = *(const bf16x8_t*)&Bsh[wj + nj * 16 + m][ch];
        #pragma unroll
        for (int mi = 0; mi < 4; mi++)
            #pragma unroll
            for (int nj = 0; nj < 4; nj++)
                acc[mi][nj] = __builtin_amdgcn_mfma_f32_16x16x32_bf16(
                    af[mi], bfr[nj], acc[mi][nj], 0, 0, 0);
    }

    // Epilogue. C/D layout: col = m (j-dir), row = q*4 + reg (i-dir).
    float sjv[4];
    #pragma unroll
    for (int nj = 0; nj < 4; nj++) sjv[nj] = sinv[j0 + wj + nj * 16 + m];
    #pragma unroll
    for (int mi = 0; mi < 4; mi++) {
        #pragma unroll
        for (int r = 0; r < 4; r++) {
            float best = -INFINITY; int bidx = 0x7fffffff;
            #pragma unroll
            for (int nj = 0; nj < 4; nj++) {
                int j = j0 + wj + nj * 16 + m;
                float v = (j < N_REAL) ? acc[mi][nj][r] * sjv[nj] : -INFINITY;
                if (v > best) { best = v; bidx = j; }
            }
            #pragma unroll
            for (int off = 1; off < 16; off <<= 1) {
                float ov = __shfl_xor(best, off);
                int   oi = __shfl_xor(bidx, off);
                if (ov > best || (ov == best && oi < bidx)) { best = ov; bidx = oi; }
            }
            if (m == 0) {
                int i = i0 + wi + mi * 16 + q * 4 + r;
                pval[(size_t)jt * N_PAD + i] = best;
                pidx[(size_t)jt * N_PAD + i] = bidx;
            }
        }
    }
}

// ---------------------------------------------------------------------------
__global__ void merge_nearest(const float* __restrict__ pval,
                              const int* __restrict__ pidx,
                              int* __restrict__ nearest, double* __restrict__ accum) {
    int n = blockIdx.x * blockDim.x + threadIdx.x;
    if (n == 0) *accum = 0.0;                  // runs before loss_kernel (stream order)
    if (n >= N_REAL) return;
    float best = -INFINITY; int bidx = 0x7fffffff;
    for (int jt = 0; jt < JTILES; jt++) {
        float v  = pval[(size_t)jt * N_PAD + n];
        int   id = pidx[(size_t)jt * N_PAD + n];
        if (v > best || (v == best && id < bidx)) { best = v; bidx = id; }
    }
    nearest[n] = bidx;
}

// ---------------------------------------------------------------------------
__global__ __launch_bounds__(256) void loss_kernel(
        const unsigned short* __restrict__ Ib, const unsigned short* __restrict__ Sb,
        const int* __restrict__ nearest, double* __restrict__ accum) {
    __shared__ float wsum[4];
    int n = blockIdx.x;
    int jn = nearest[n];
    const uint4* ip = (const uint4*)(Ib + (size_t)n  * D_PAD);
    const uint4* sp = (const uint4*)(Sb + (size_t)jn * D_PAD);
    float s = 0.f;
    for (int k = threadIdx.x; k < D_PAD / 8; k += 256) {
        uint4 a = ip[k], b = sp[k];
        float d0 = bflo(a.x) - bflo(b.x), d1 = bfhi(a.x) - bfhi(b.x);
        float d2 = bflo(a.y) - bflo(b.y), d3 = bfhi(a.y) - bfhi(b.y);
        float d4 = bflo(a.z) - bflo(b.z), d5 = bfhi(a.z) - bfhi(b.z);
        float d6 = bflo(a.w) - bflo(b.w), d7 = bfhi(a.w) - bfhi(b.w);
        s = fmaf(d0, d0, s); s = fmaf(d1, d1, s);
        s = fmaf(d2, d2, s); s = fmaf(d3, d3, s);
        s = fmaf(d4, d4, s); s = fmaf(d5, d5, s);
        s = fmaf(d6, d6, s); s = fmaf(d7, d7, s);
    }
    #pragma unroll
    for (int off = 32; off > 0; off >>= 1) s += __shfl_xor(s, off);
    int lane = threadIdx.x & 63, wv = threadIdx.x >> 6;
    if (lane == 0) wsum[wv] = s;
    __syncthreads();
    if (threadIdx.x == 0) {
        double t = (double)wsum[0] + (double)wsum[1] + (double)wsum[2] + (double)wsum[3];
        atomicAdd(accum, t);
    }
}

__global__ void finalize(const double* __restrict__ accum, float* __restrict__ out) {
    out[0] = (float)(accum[0] / (double)((long long)D_REAL * N_REAL));
}

// ---------------------------------------------------------------------------
extern "C" void kernel_launch(void* const* d_in, const int* in_sizes, int n_in,
                              void* d_out, int out_size, void* d_ws, size_t ws_size,
                              hipStream_t stream) {
    const float* style_resp = (const float*)d_in[0];
    const float* style_map  = (const float*)d_in[1];
    const float* output_map = (const float*)d_in[2];
    const float* model_resp = (const float*)d_in[3];
    float* out = (float*)d_out;

    unsigned short* Sb = (unsigned short*)d_ws;
    unsigned short* Ib = Sb + (size_t)D_PAD * N_PAD;
    float* sinv    = (float*)(Ib + (size_t)D_PAD * N_PAD);
    float* pval    = sinv + N_PAD;
    int*   pidx    = (int*)(pval + (size_t)JTILES * N_PAD);
    int*   nearest = pidx + (size_t)JTILES * N_PAD;
    double* accum  = (double*)(nearest + N_PAD);

    dim3 rgrid(85, 72);                        // u-rows x 32-d tiles (d < 2304)
    build_resp<<<rgrid, 256, 0, stream>>>(style_resp, Sb);
    build_map<<<(N_REAL * 32 + 255) / 256, 256, 0, stream>>>(style_map, Sb);
    build_resp<<<rgrid, 256, 0, stream>>>(model_resp, Ib);
    build_map<<<(N_REAL * 32 + 255) / 256, 256, 0, stream>>>(output_map, Ib);

    col_norms<<<N_PAD / 4, 256, 0, stream>>>(Sb, sinv);

    gemm_argmax<<<STILES * STILES * 16, 256, 0, stream>>>(Sb, Ib, sinv, pval, pidx);

    merge_nearest<<<(N_REAL + 255) / 256, 256, 0, stream>>>(pval, pidx, nearest, accum);

    loss_kernel<<<N_REAL, 256, 0, stream>>>(Ib, Sb, nearest, accum);
    finalize<<<1, 1, 0, stream>>>(accum, out);
}

// Round 5
// 625.444 us; speedup vs baseline: 4.7709x; 1.0727x over previous
//
#include <hip/hip_runtime.h>
#include <float.h>
#include <math.h>

// Problem constants
#define D_REAL 2331   // 259 channels * 3*3 patch
#define D_PAD  2336   // multiple of 32 (MFMA K-tile)
#define N_REAL 7225   // 85*85 patches
#define N_PAD  7296   // 57*128
#define JTILES 57
#define ITILES 57
#define STILES 15     // ceil(57/4) supertile grid per dim
#define KITERS (D_PAD / 32)   // 73

typedef __attribute__((ext_vector_type(8))) short bf16x8_t;  // 8 bf16 = 4 VGPRs
typedef __attribute__((ext_vector_type(4))) float f32x4_t;   // MFMA C/D

__device__ __forceinline__ unsigned short f2bf(float x) {
    union { float f; unsigned int u; } v; v.f = x;
    unsigned int r = v.u + 0x7FFFu + ((v.u >> 16) & 1u);   // RNE
    return (unsigned short)(r >> 16);
}
__device__ __forceinline__ float bflo(unsigned int u) {
    union { unsigned int x; float f; } v; v.x = u << 16; return v.f;
}
__device__ __forceinline__ float bfhi(unsigned int u) {
    union { unsigned int x; float f; } v; v.x = u & 0xFFFF0000u; return v.f;
}

#define GLOAD_LDS16(g, l) __builtin_amdgcn_global_load_lds( \
    (const __attribute__((address_space(1))) void*)(g),     \
    (__attribute__((address_space(3))) void*)(l), 16, 0, 0)

// ---------------------------------------------------------------------------
// Resp part of Pb[n][d] (d < 2304). Block = (u-row, 32-d tile, which-matrix).
__global__ __launch_bounds__(256) void build_resp(
        const float* __restrict__ respS, const float* __restrict__ respI,
        unsigned short* __restrict__ PbS, unsigned short* __restrict__ PbI) {
    const float* resp = blockIdx.z ? respI : respS;
    unsigned short* Pb = blockIdx.z ? PbI : PbS;
    __shared__ float slab[5 * 768];            // [cc][rr][col], 15 KB max
    const int u  = blockIdx.x;                 // 0..84
    const int d0 = blockIdx.y * 32;            // 0..2272
    const int c0 = d0 / 9;
    const int cN = (d0 + 31) / 9 - c0 + 1;     // <= 5
    const int total = cN * 768;
    for (int idx = threadIdx.x; idx < total; idx += 256) {
        int cc = idx / 768;
        int rem = idx - cc * 768;              // (row-3u)*256 + col
        slab[idx] = resp[(((size_t)(c0 + cc)) << 16) + ((size_t)(3 * u) << 8) + rem];
    }
    __syncthreads();
    const int dl = threadIdx.x & 31;
    const int d = d0 + dl;
    const int c = d / 9, r9 = d - c * 9, p = r9 / 3, q = r9 - p * 3;
    const int base = (c - c0) * 768 + p * 256 + q;
    const int v0 = threadIdx.x >> 5;           // 0..7
    size_t out = (size_t)(u * 85) * D_PAD + d0 + dl;
    for (int v = v0; v < 85; v += 8)
        Pb[out + (size_t)v * D_PAD] = f2bf(slab[base + 3 * v]);
}

// ---------------------------------------------------------------------------
// Map part: d in [2304, 2336): 27 real map rows (50 * avgpool4) + 5 zero pad.
__global__ __launch_bounds__(256) void build_map(
        const float* __restrict__ mapS, const float* __restrict__ mapI,
        unsigned short* __restrict__ PbS, unsigned short* __restrict__ PbI) {
    const float* map = blockIdx.y ? mapI : mapS;
    unsigned short* Pb = blockIdx.y ? PbI : PbS;
    int t = blockIdx.x * 256 + threadIdx.x;
    int n = t >> 5, dm = t & 31;
    if (n >= N_REAL) return;
    float val = 0.f;
    if (dm < 27) {
        int u = n / 85, v = n - u * 85;
        int ch = dm / 9, r9 = dm - ch * 9, p = r9 / 3, q = r9 - p * 3;
        const float* mp = map + ((size_t)ch << 20)
                              + ((size_t)((3 * u + p) * 4) << 10)
                              + (size_t)((3 * v + q) * 4);
        float s = 0.f;
        #pragma unroll
        for (int a = 0; a < 4; a++)
            #pragma unroll
            for (int b = 0; b < 4; b++) s += mp[a * 1024 + b];
        val = 3.125f * s;                      // 50 * (1/16)
    }
    Pb[(size_t)n * D_PAD + 2304 + dm] = f2bf(val);
}

// ---------------------------------------------------------------------------
// sinv[n] = 1/||S[:,n]||; also zeroes the loss accumulator (stream-ordered
// well before loss_kernel).
__global__ __launch_bounds__(256) void col_norms(const unsigned short* __restrict__ Sb,
                                                 float* __restrict__ sinv,
                                                 double* __restrict__ accum) {
    if (blockIdx.x == 0 && threadIdx.x == 0) *accum = 0.0;
    int n = blockIdx.x * 4 + (threadIdx.x >> 6);
    int lane = threadIdx.x & 63;
    const uint4* sp = (const uint4*)(Sb + (size_t)n * D_PAD);
    float s = 0.f;
    for (int k = lane; k < D_PAD / 8; k += 64) {
        uint4 a = sp[k];
        float x0 = bflo(a.x), x1 = bfhi(a.x), x2 = bflo(a.y), x3 = bfhi(a.y);
        float x4 = bflo(a.z), x5 = bfhi(a.z), x6 = bflo(a.w), x7 = bfhi(a.w);
        s = fmaf(x0, x0, s); s = fmaf(x1, x1, s);
        s = fmaf(x2, x2, s); s = fmaf(x3, x3, s);
        s = fmaf(x4, x4, s); s = fmaf(x5, x5, s);
        s = fmaf(x6, x6, s); s = fmaf(x7, x7, s);
    }
    #pragma unroll
    for (int off = 32; off > 0; off >>= 1) s += __shfl_xor(s, off);
    if (lane == 0) sinv[n] = (n < N_REAL) ? rsqrtf(s) : 0.f;
}

// ---------------------------------------------------------------------------
// MFMA GEMM + fused argmax. Double-buffered LDS, ONE barrier per K-iter:
// the vmcnt(0) drain at the barrier waits on loads issued a full compute
// phase earlier, instead of immediately after issue (the R2-R4 structure).
// XOR-swizzled LDS chunks (conflict-free) + 4x4 supertile swizzle (L2 reuse).
__global__ __launch_bounds__(256) void gemm_argmax(
        const unsigned short* __restrict__ Sb, const unsigned short* __restrict__ Ib,
        const float* __restrict__ sinv,
        float* __restrict__ pval, int* __restrict__ pidx) {
    const int lb = blockIdx.x;
    const int sup = lb >> 4, win = lb & 15;
    const int it4 = (sup / STILES) * 4 + (win & 3);
    const int jt4 = (sup % STILES) * 4 + (win >> 2);
    if (it4 >= ITILES || jt4 >= JTILES) return;   // uniform: no barrier executed
    const int i0 = it4 * 128, j0 = jt4 * 128;

    __shared__ __align__(16) unsigned short Ash[2][128][32];
    __shared__ __align__(16) unsigned short Bsh[2][128][32];
    const int tid = threadIdx.x;
    const int L = tid & 63, w = tid >> 6;
    const int m = L & 15, q = L >> 4;
    const int wi = (w >> 1) * 64, wj = (w & 1) * 64;

    f32x4_t acc[4][4];
    #pragma unroll
    for (int a = 0; a < 4; a++)
        #pragma unroll
        for (int b = 0; b < 4; b++) acc[a][b] = (f32x4_t){0.f, 0.f, 0.f, 0.f};

    // staging: lane L -> LDS row rl=L>>2, chunk pos L&3; global chunk XOR-swizzled
    const int rl = L >> 2;
    const int ck = (L & 3) ^ ((rl >> 1) & 3);
    const unsigned short* ga = Sb + (size_t)(i0 + w * 32 + rl) * D_PAD + (ck << 3);
    const unsigned short* gb = Ib + (size_t)(j0 + w * 32 + rl) * D_PAD + (ck << 3);

    const int ch = (q ^ ((m >> 1) & 3)) << 3;   // read-side swizzled chunk

    // prologue: tile 0 -> buffer 0
    {
        unsigned short* nA = &Ash[0][w * 32][0];
        unsigned short* nB = &Bsh[0][w * 32][0];
        GLOAD_LDS16(ga, nA);
        GLOAD_LDS16(ga + (size_t)16 * D_PAD, nA + 16 * 32);
        GLOAD_LDS16(gb, nB);
        GLOAD_LDS16(gb + (size_t)16 * D_PAD, nB + 16 * 32);
        ga += 32; gb += 32;
    }

    for (int kt = 0; kt < KITERS; kt++) {
        const int cur = kt & 1;
        __syncthreads();   // drains vmcnt -> buf[cur] ready; buf[cur^1] free
        if (kt + 1 < KITERS) {
            unsigned short* nA = &Ash[cur ^ 1][w * 32][0];
            unsigned short* nB = &Bsh[cur ^ 1][w * 32][0];
            GLOAD_LDS16(ga, nA);
            GLOAD_LDS16(ga + (size_t)16 * D_PAD, nA + 16 * 32);
            GLOAD_LDS16(gb, nB);
            GLOAD_LDS16(gb + (size_t)16 * D_PAD, nB + 16 * 32);
            ga += 32; gb += 32;
        }
        __builtin_amdgcn_sched_barrier(0);   // pin prefetch issue before compute

        bf16x8_t af[4], bfr[4];
        #pragma unroll
        for (int mi = 0; mi < 4; mi++)
            af[mi] = *(const bf16x8_t*)&Ash[cur][wi + mi * 16 + m][ch];
        #pragma unroll
        for (int nj = 0; nj < 4; nj++)
            bfr[nj] = *(const bf16x8_t*)&Bsh[cur][wj + nj * 16 + m][ch];
        #pragma unroll
        for (int mi = 0; mi < 4; mi++)
            #pragma unroll
            for (int nj = 0; nj < 4; nj++)
                acc[mi][nj] = __builtin_amdgcn_mfma_f32_16x16x32_bf16(
                    af[mi], bfr[nj], acc[mi][nj], 0, 0, 0);
    }

    // Epilogue. C/D layout: col = m (j-dir), row = q*4 + reg (i-dir).
    float sjv[4];
    #pragma unroll
    for (int nj = 0; nj < 4; nj++) sjv[nj] = sinv[j0 + wj + nj * 16 + m];
    #pragma unroll
    for (int mi = 0; mi < 4; mi++) {
        #pragma unroll
        for (int r = 0; r < 4; r++) {
            float best = -INFINITY; int bidx = 0x7fffffff;
            #pragma unroll
            for (int nj = 0; nj < 4; nj++) {   // j ascending -> '>' keeps smallest
                int j = j0 + wj + nj * 16 + m;
                float v = (j < N_REAL) ? acc[mi][nj][r] * sjv[nj] : -INFINITY;
                if (v > best) { best = v; bidx = j; }
            }
            #pragma unroll
            for (int off = 1; off < 16; off <<= 1) {
                float ov = __shfl_xor(best, off);
                int   oi = __shfl_xor(bidx, off);
                if (ov > best || (ov == best && oi < bidx)) { best = ov; bidx = oi; }
            }
            if (m == 0) {
                int i = i0 + wi + mi * 16 + q * 4 + r;
                pval[(size_t)jt4 * N_PAD + i] = best;
                pidx[(size_t)jt4 * N_PAD + i] = bidx;
            }
        }
    }
}

// ---------------------------------------------------------------------------
// Fused merge + loss. Block = one n: reduce the 57 per-j-tile argmax
// partials in-wave, then accumulate (I[:,n] - S[:,nearest])^2.
__global__ __launch_bounds__(256) void loss_kernel(
        const unsigned short* __restrict__ Ib, const unsigned short* __restrict__ Sb,
        const float* __restrict__ pval, const int* __restrict__ pidx,
        double* __restrict__ accum) {
    __shared__ float wsum[4];
    __shared__ int sjn;
    const int n = blockIdx.x;
    if (threadIdx.x < 64) {                    // wave 0: merge 57 partials
        float v = -INFINITY; int id = 0x7fffffff;
        if (threadIdx.x < JTILES) {
            v  = pval[(size_t)threadIdx.x * N_PAD + n];
            id = pidx[(size_t)threadIdx.x * N_PAD + n];
        }
        #pragma unroll
        for (int off = 32; off > 0; off >>= 1) {
            float ov = __shfl_xor(v, off);
            int   oi = __shfl_xor(id, off);
            if (ov > v || (ov == v && oi < id)) { v = ov; id = oi; }
        }
        if (threadIdx.x == 0) sjn = id;
    }
    __syncthreads();
    const int jn = sjn;
    const uint4* ip = (const uint4*)(Ib + (size_t)n  * D_PAD);
    const uint4* sp = (const uint4*)(Sb + (size_t)jn * D_PAD);
    float s = 0.f;
    for (int k = threadIdx.x; k < D_PAD / 8; k += 256) {
        uint4 a = ip[k], b = sp[k];
        float d0 = bflo(a.x) - bflo(b.x), d1 = bfhi(a.x) - bfhi(b.x);
        float d2 = bflo(a.y) - bflo(b.y), d3 = bfhi(a.y) - bfhi(b.y);
        float d4 = bflo(a.z) - bflo(b.z), d5 = bfhi(a.z) - bfhi(b.z);
        float d6 = bflo(a.w) - bflo(b.w), d7 = bfhi(a.w) - bfhi(b.w);
        s = fmaf(d0, d0, s); s = fmaf(d1, d1, s);
        s = fmaf(d2, d2, s); s = fmaf(d3, d3, s);
        s = fmaf(d4, d4, s); s = fmaf(d5, d5, s);
        s = fmaf(d6, d6, s); s = fmaf(d7, d7, s);
    }
    #pragma unroll
    for (int off = 32; off > 0; off >>= 1) s += __shfl_xor(s, off);
    int lane = threadIdx.x & 63, wv = threadIdx.x >> 6;
    if (lane == 0) wsum[wv] = s;
    __syncthreads();
    if (threadIdx.x == 0) {
        double t = (double)wsum[0] + (double)wsum[1] + (double)wsum[2] + (double)wsum[3];
        atomicAdd(accum, t);
    }
}

__global__ void finalize(const double* __restrict__ accum, float* __restrict__ out) {
    out[0] = (float)(accum[0] / (double)((long long)D_REAL * N_REAL));
}

// ---------------------------------------------------------------------------
extern "C" void kernel_launch(void* const* d_in, const int* in_sizes, int n_in,
                              void* d_out, int out_size, void* d_ws, size_t ws_size,
                              hipStream_t stream) {
    const float* style_resp = (const float*)d_in[0];
    const float* style_map  = (const float*)d_in[1];
    const float* output_map = (const float*)d_in[2];
    const float* model_resp = (const float*)d_in[3];
    float* out = (float*)d_out;

    unsigned short* Sb = (unsigned short*)d_ws;
    unsigned short* Ib = Sb + (size_t)D_PAD * N_PAD;
    float* sinv    = (float*)(Ib + (size_t)D_PAD * N_PAD);
    float* pval    = sinv + N_PAD;
    int*   pidx    = (int*)(pval + (size_t)JTILES * N_PAD);
    double* accum  = (double*)(pidx + (size_t)JTILES * N_PAD);

    build_resp<<<dim3(85, 72, 2), 256, 0, stream>>>(style_resp, model_resp, Sb, Ib);
    build_map<<<dim3((N_REAL * 32 + 255) / 256, 2), 256, 0, stream>>>(style_map, output_map, Sb, Ib);

    col_norms<<<N_PAD / 4, 256, 0, stream>>>(Sb, sinv, accum);

    gemm_argmax<<<STILES * STILES * 16, 256, 0, stream>>>(Sb, Ib, sinv, pval, pidx);

    loss_kernel<<<N_REAL, 256, 0, stream>>>(Ib, Sb, pval, pidx, accum);
    finalize<<<1, 1, 0, stream>>>(accum, out);
}